// Round 2
// 654.359 us; speedup vs baseline: 1.5783x; 1.5783x over previous
//
#include <hip/hip_runtime.h>
#include <stdint.h>

// R6 (= R5 resubmit + VGPR hardening): block-cooperative K/V staging.
// Theory: attn was latency/L3-bandwidth bound (MfmaUtil 5.9%, VALUBusy 12.7%,
// HBM 2.6% -- nothing saturated; ~26k cyc/iter vs ~2k of issue work). Each wave
// privately streamed 24KB/iter from L2/L3 (9.2 TB/s aggregate) with serial
// load->MFMA chains. Fix: 8-wave blocks (128 Q rows) share one 32-key K/V chunk,
// double-buffer staged to LDS via global_load_lds(16B); per-wave global traffic
// drops 24KB -> 8KB (PE only, L2-resident), per-block staging 16KB/iter.
//  - Kb2/Vt2 inner order [quad][l15] so LDS fragment reads are lane-linear
//    (addr = lane*16B) -- conflict-free by construction.
//  - V frags loaded 4+4 interleaved with PV halves (V is LDS-resident now;
//    early-load rationale gone) to keep peak VGPR under the 128 budget of
//    __launch_bounds__(512,4) -> 2 blocks/CU.
//  - keeps: fixed-max softmax, XCD swizzle, carried pos tile + shear shuffles.

#define BH_N   128
#define MQ     512
#define LSPAN  2048
#define DH     128
#define KLEN   2560   // MQ + LSPAN
#define NC     68     // block chunk count: covers keys [M0, M0+2175]

typedef __attribute__((ext_vector_type(8))) short bf16x8;
typedef __attribute__((ext_vector_type(4))) float f32x4;

__device__ __forceinline__ ushort f32_to_bf16(float f) {
    union { float f; uint32_t u; } v; v.f = f;
    uint32_t u = v.u;
    u += 0x7fffu + ((u >> 16) & 1u);   // RNE; inputs finite
    return (ushort)(u >> 16);
}

// Q fp32 -> bf16, row-major (A-frags are contiguous already)
__global__ __launch_bounds__(256)
void conv_kernel(const float4* __restrict__ in, ushort4* __restrict__ out, int n4) {
    int i = blockIdx.x * blockDim.x + threadIdx.x;
    if (i >= n4) return;
    float4 f = in[i];
    ushort4 o;
    o.x = f32_to_bf16(f.x); o.y = f32_to_bf16(f.y);
    o.z = f32_to_bf16(f.z); o.w = f32_to_bf16(f.w);
    out[i] = o;
}

// pe (1,128,2048) fp32 [d][l] -> PEt bf16 [l][d]
__global__ __launch_bounds__(256)
void pe_kernel(const float* __restrict__ pe, ushort* __restrict__ pet) {
    int idx = blockIdx.x * blockDim.x + threadIdx.x;   // over 2048*128
    int d = idx & (DH - 1);
    int l = idx >> 7;
    pet[idx] = f32_to_bf16(pe[(size_t)d * LSPAN + l]);
}

// K fp32 [b][row][d] -> Kb2 bf16 [b][g:160][ks:4][quad:4][l15:16][j:8]
// element [b][g][ks][q][n][j] = K[b][g*16+n][ks*32+q*8+j]
// (inner order quad-major so attn's LDS read addr == lane*16B)
__global__ __launch_bounds__(256)
void k2_kernel(const float* __restrict__ K, ushort* __restrict__ Kb2) {
    int b = blockIdx.x / 160, g = blockIdx.x % 160;
    int t = threadIdx.x;
    int row = t >> 4;              // 0..15
    int d0  = (t & 15) * 8;        // 8 d's: same (ks, quad), j=0..7
    const float* src = K + ((size_t)b * KLEN + g * 16 + row) * DH + d0;
    float4 f0 = *reinterpret_cast<const float4*>(src);
    float4 f1 = *reinterpret_cast<const float4*>(src + 4);
    ushort o[8];
    o[0]=f32_to_bf16(f0.x); o[1]=f32_to_bf16(f0.y); o[2]=f32_to_bf16(f0.z); o[3]=f32_to_bf16(f0.w);
    o[4]=f32_to_bf16(f1.x); o[5]=f32_to_bf16(f1.y); o[6]=f32_to_bf16(f1.z); o[7]=f32_to_bf16(f1.w);
    int ks = d0 >> 5, quad = (d0 >> 3) & 3;
    ushort* dst = Kb2 + ((size_t)(b * 160 + g) * 4 + ks) * 512 + (quad * 16 + row) * 8;
    *reinterpret_cast<ushort4*>(dst)     = *reinterpret_cast<ushort4*>(&o[0]);
    *reinterpret_cast<ushort4*>(dst + 4) = *reinterpret_cast<ushort4*>(&o[4]);
}

// V fp32 [b][row][d] -> Vt2 bf16 [b][rb:80][db:8][quad:4][l15:16][j:8]
// element [b][rb][db][q][n][j] = V[b][rb*32+q*8+j][db*16+n]
__global__ __launch_bounds__(256)
void vt2_kernel(const float* __restrict__ V, ushort* __restrict__ Vt2) {
    int b  = blockIdx.x / 80;
    int rb = blockIdx.x % 80;
    __shared__ ushort tile[32][132];   // [row][d], +4 pad
    int t = threadIdx.x;
    int row = t >> 3;                  // 0..31
    int d0  = (t & 7) * 16;
    const float* src = V + ((size_t)b * KLEN + rb * 32 + row) * DH + d0;
    #pragma unroll
    for (int p = 0; p < 4; ++p) {
        float4 f = *reinterpret_cast<const float4*>(src + p * 4);
        ushort4 o;
        o.x = f32_to_bf16(f.x); o.y = f32_to_bf16(f.y);
        o.z = f32_to_bf16(f.z); o.w = f32_to_bf16(f.w);
        *reinterpret_cast<ushort4*>(&tile[row][d0 + p * 4]) = o;
    }
    __syncthreads();
    #pragma unroll
    for (int p = 0; p < 2; ++p) {
        int m = p * 256 + t;           // 0..511 output 16B chunks, layout-linear
        int db = m >> 6, quad = (m >> 4) & 3, l15 = m & 15;
        int d = db * 16 + l15;
        ushort o[8];
        #pragma unroll
        for (int j = 0; j < 8; ++j) o[j] = tile[quad * 8 + j][d];
        ushort* dst = Vt2 + (size_t)(b * 80 + rb) * 4096 + (size_t)m * 8;
        *reinterpret_cast<ushort4*>(dst)     = *reinterpret_cast<ushort4*>(&o[0]);
        *reinterpret_cast<ushort4*>(dst + 4) = *reinterpret_cast<ushort4*>(&o[4]);
    }
}

#define GLOAD_LDS16(gp, lp) \
    __builtin_amdgcn_global_load_lds( \
        (const __attribute__((address_space(1))) void*)(gp), \
        (__attribute__((address_space(3))) void*)(lp), 16, 0, 0)

__global__ __launch_bounds__(512, 4)
void attn_kernel(const ushort* __restrict__ Qb, const ushort* __restrict__ Kb2,
                 const ushort* __restrict__ Vt2, const ushort* __restrict__ PEt,
                 float* __restrict__ Out) {
    const int wv   = threadIdx.x >> 6;          // 0..7
    const int lane = threadIdx.x & 63;
    const int tid  = threadIdx.x;
    const int xcd  = blockIdx.x & 7;            // same-b blocks share an XCD
    const int yy   = blockIdx.x >> 3;           // 0..63
    const int b    = xcd * 16 + (yy >> 2);
    const int M0   = (yy & 3) * 128;
    const int m0   = M0 + wv * 16;
    const int l15  = lane & 15;
    const int quad = lane >> 4;

    __shared__ __align__(16) ushort s_kv[2][8192];    // [K 4096 | V 4096] dbuf
    __shared__ __align__(16) ushort s_p[8][16][40];

    const ushort* kb = Kb2 + (size_t)b * (160 * 4 * 512);
    const ushort* vb = Vt2 + (size_t)b * (80 * 4096);
    const int g0 = M0 >> 4;                     // 16-row tile base of this block
    const int r0 = M0 >> 5;                     // 32-row chunk base

    // shear shuffle constants: s1[r] = 16 - quad*4 - r
    int srcL[4], hi[4];
    #pragma unroll
    for (int r = 0; r < 4; ++r) {
        int t0 = l15 + 16 - quad * 4 - r;       // in [1,31]
        srcL[r] = (lane & 48) | (t0 & 15);
        hi[r]   = t0 & 16;
    }

    bf16x8 qfrag[4];
    {
        const ushort* qrow = Qb + ((size_t)(b * MQ + m0 + l15)) * DH + quad * 8;
        #pragma unroll
        for (int ks = 0; ks < 4; ++ks)
            qfrag[ks] = *reinterpret_cast<const bf16x8*>(qrow + ks * 32);
    }

    f32x4 Oacc[8];
    #pragma unroll
    for (int db = 0; db < 8; ++db) Oacc[db] = (f32x4){0.f, 0.f, 0.f, 0.f};
    float lsum[4];
    #pragma unroll
    for (int r = 0; r < 4; ++r) lsum[r] = 0.f;

    const float SC2  = 0.08838834764831845f * 1.4426950408889634f;
    const float SMAX = 24.0f;

    // aligned pos tile g covers pe rows l = 16g + n (n = lane's l15)
    auto pos_tile = [&](int g) -> f32x4 {
        f32x4 acc = (f32x4){0.f, 0.f, 0.f, 0.f};
        int l = 16 * g + l15;
        l = l < 0 ? 0 : (l > LSPAN - 1 ? LSPAN - 1 : l);   // masked downstream
        const ushort* prow = PEt + (size_t)l * DH + quad * 8;
        #pragma unroll
        for (int ks = 0; ks < 4; ++ks) {
            bf16x8 bf = *reinterpret_cast<const bf16x8*>(prow + ks * 32);
            acc = __builtin_amdgcn_mfma_f32_16x16x32_bf16(qfrag[ks], bf, acc, 0, 0, 0);
        }
        return acc;
    };

    const int c_lo = wv >> 1;                   // wave active window [c_lo, c_lo+64]
    f32x4 pext0, pext1, pext2;
    pext2 = pos_tile(2 * c_lo - wv - 1);        // carry-in for first active chunk

    // prologue: stage chunk 0 (thread t copies bytes [16t,16t+16) of each 8KB region)
    GLOAD_LDS16(kb + (size_t)g0 * 2048 + (size_t)tid * 8, &s_kv[0][wv * 512]);
    GLOAD_LDS16(vb + (size_t)r0 * 4096 + (size_t)tid * 8, &s_kv[0][4096 + wv * 512]);
    __syncthreads();   // drains vmcnt(0): chunk 0 resident

    for (int c = 0; c < NC; ++c) {
        const int p = c & 1;

        // ---- issue next-chunk staging (lands under this iter's compute)
        if (c + 1 < NC) {
            GLOAD_LDS16(kb + (size_t)(g0 + 2 * (c + 1)) * 2048 + (size_t)tid * 8,
                        &s_kv[p ^ 1][wv * 512]);
            GLOAD_LDS16(vb + (size_t)(r0 + (c + 1)) * 4096 + (size_t)tid * 8,
                        &s_kv[p ^ 1][4096 + wv * 512]);
        }

        if ((unsigned)(c - c_lo) <= 64u) {      // wave-uniform band check
            const int G    = 2 * c - wv;
            const int rel0 = c * 32 - wv * 16;
            pext0 = pext2;

            const ushort* lkb = &s_kv[p][0];
            const ushort* lvb = &s_kv[p][4096];

            // ---- K frags from LDS (lane-linear, conflict-free)
            bf16x8 kf[8];
            #pragma unroll
            for (int cb = 0; cb < 2; ++cb)
                #pragma unroll
                for (int ks = 0; ks < 4; ++ks)
                    kf[cb * 4 + ks] = *reinterpret_cast<const bf16x8*>(
                        lkb + ((cb * 4 + ks) * 64 + lane) * 8);

            // ---- pos tiles G, G+1 (8 MFMA; tile G-1 carried)
            pext1 = pos_tile(G);
            pext2 = pos_tile(G + 1);

            // ---- content scores
            f32x4 qk[2];
            #pragma unroll
            for (int cb = 0; cb < 2; ++cb) {
                qk[cb] = (f32x4){0.f, 0.f, 0.f, 0.f};
                #pragma unroll
                for (int ks = 0; ks < 4; ++ks)
                    qk[cb] = __builtin_amdgcn_mfma_f32_16x16x32_bf16(qfrag[ks], kf[cb * 4 + ks], qk[cb], 0, 0, 0);
            }

            // ---- shear: rot[cb][r] = pext[cb][r] from lane (quad, (l15+s1)&15)
            float rot[3][4];
            #pragma unroll
            for (int r = 0; r < 4; ++r) {
                rot[0][r] = __shfl(pext0[r], srcL[r]);
                rot[1][r] = __shfl(pext1[r], srcL[r]);
                rot[2][r] = __shfl(pext2[r], srcL[r]);
            }

            // ---- combine + band mask + fixed-max exp
            #pragma unroll
            for (int cbo = 0; cbo < 2; ++cbo) {
                #pragma unroll
                for (int r = 0; r < 4; ++r) {
                    float posv = hi[r] ? rot[cbo + 1][r] : rot[cbo][r];
                    int l = rel0 - 16 + cbo * 16 + (l15 + 16 - quad * 4 - r);
                    float val = ((unsigned)l < (unsigned)LSPAN)
                              ? fmaf(qk[cbo][r] + posv, SC2, -SMAX) : -1e30f;
                    float pv = exp2f(val);
                    lsum[r] += pv;
                    s_p[wv][quad * 4 + r][cbo * 16 + l15] = f32_to_bf16(pv);
                }
            }

            // ---- PV (V frags from LDS, 4+4 to cap VGPR peak)
            bf16x8 pfrag = *reinterpret_cast<const bf16x8*>(&s_p[wv][l15][quad * 8]);
            #pragma unroll
            for (int h = 0; h < 2; ++h) {
                bf16x8 vf[4];
                #pragma unroll
                for (int d4 = 0; d4 < 4; ++d4)
                    vf[d4] = *reinterpret_cast<const bf16x8*>(
                        lvb + ((h * 4 + d4) * 64 + lane) * 8);
                #pragma unroll
                for (int d4 = 0; d4 < 4; ++d4)
                    Oacc[h * 4 + d4] = __builtin_amdgcn_mfma_f32_16x16x32_bf16(
                        pfrag, vf[d4], Oacc[h * 4 + d4], 0, 0, 0);
            }
        }

        __syncthreads();   // drains staging vmcnt + guards dbuf reuse
    }

    // ---- epilogue
    #pragma unroll
    for (int off = 1; off < 16; off <<= 1)
        #pragma unroll
        for (int r = 0; r < 4; ++r)
            lsum[r] += __shfl_xor(lsum[r], off);
    #pragma unroll
    for (int r = 0; r < 4; ++r) lsum[r] = 1.0f / lsum[r];

    #pragma unroll
    for (int db = 0; db < 8; ++db)
        #pragma unroll
        for (int r = 0; r < 4; ++r)
            Out[((size_t)(b * MQ + m0 + quad * 4 + r)) * DH + db * 16 + l15]
                = Oacc[db][r] * lsum[r];
}

extern "C" void kernel_launch(void* const* d_in, const int* in_sizes, int n_in,
                              void* d_out, int out_size, void* d_ws, size_t ws_size,
                              hipStream_t stream) {
    const float* Qf  = (const float*)d_in[0];
    const float* Kf  = (const float*)d_in[1];
    const float* Vf  = (const float*)d_in[2];
    const float* PEf = (const float*)d_in[3];
    float* Out = (float*)d_out;

    // ws layout (ushorts): Vt2 | Kb2 | Qb | PEt
    ushort* Vt2 = (ushort*)d_ws;                         // 80*8*512*128 = 41,943,040
    ushort* Kb2 = Vt2 + (size_t)41943040;                // 160*4*512*128 = 41,943,040
    ushort* Qb  = Kb2 + (size_t)41943040;                //  8,388,608
    ushort* PEt = Qb + (size_t)8388608;                  //    262,144

    hipLaunchKernelGGL(k2_kernel, dim3(128 * 160), dim3(256), 0, stream, Kf, Kb2);
    hipLaunchKernelGGL(vt2_kernel, dim3(128 * 80), dim3(256), 0, stream, Vf, Vt2);
    hipLaunchKernelGGL(conv_kernel, dim3(8192), dim3(256), 0, stream,
                       (const float4*)Qf, (ushort4*)Qb, 2097152);
    hipLaunchKernelGGL(pe_kernel, dim3(1024), dim3(256), 0, stream, PEf, PEt);
    hipLaunchKernelGGL(attn_kernel, dim3(512), dim3(512), 0, stream,
                       Qb, Kb2, Vt2, PEt, Out);
}